// Round 2
// baseline (428.035 us; speedup 1.0000x reference)
//
#include <hip/hip_runtime.h>

#define THREADS 256

typedef unsigned short u16;

__device__ inline float bf2f(u16 u) {
  union { unsigned int i; float f; } c;
  c.i = ((unsigned int)u) << 16;
  return c.f;
}
__device__ inline u16 f2bf(float f) {
  union { float f; unsigned int i; } c;
  c.f = f;
  unsigned int r = c.i + 0x7fff + ((c.i >> 16) & 1);  // RNE
  return (u16)(r >> 16);
}

// ---------------- graph build ----------------

__global__ void k_zero(int* __restrict__ p, int n) {
  int i = blockIdx.x * blockDim.x + threadIdx.x;
  if (i < n) p[i] = 0;
}

__global__ void k_count(const int* __restrict__ dst, int* __restrict__ deg, int E) {
  int stride = gridDim.x * blockDim.x;
  for (int e = blockIdx.x * blockDim.x + threadIdx.x; e < E; e += stride)
    atomicAdd(&deg[dst[e]], 1);
}

__global__ void k_scan1(const int* __restrict__ deg, int* __restrict__ rowptr,
                        int* __restrict__ bsum, int n) {
  __shared__ int s[256];
  int t = threadIdx.x;
  int i = blockIdx.x * 256 + t;
  int v = (i < n) ? deg[i] : 0;
  s[t] = v;
  __syncthreads();
  for (int off = 1; off < 256; off <<= 1) {
    int x = (t >= off) ? s[t - off] : 0;
    __syncthreads();
    s[t] += x;
    __syncthreads();
  }
  if (i < n) rowptr[i] = s[t] - v;  // exclusive within block
  if (t == 255) bsum[blockIdx.x] = s[255];
}

__global__ void k_scan2(int* __restrict__ bsum, int nb) {
  __shared__ int s[512];
  int t = threadIdx.x;
  int v = (t < nb) ? bsum[t] : 0;
  s[t] = v;
  __syncthreads();
  for (int off = 1; off < 512; off <<= 1) {
    int x = (t >= off) ? s[t - off] : 0;
    __syncthreads();
    s[t] += x;
    __syncthreads();
  }
  if (t < nb) bsum[t] = s[t] - v;  // exclusive
}

__global__ void k_scan3(int* __restrict__ rowptr, int* __restrict__ cursor,
                        const int* __restrict__ bsum, const int* __restrict__ deg,
                        float* __restrict__ dinv, int n, int E) {
  int i = blockIdx.x * blockDim.x + threadIdx.x;
  if (i < n) {
    int r = rowptr[i] + bsum[i >> 8];
    rowptr[i] = r;
    cursor[i] = r;
    dinv[i] = rsqrtf((float)(deg[i] + 1));  // +1 self-loop
  }
  if (i == 0) rowptr[n] = E;
}

__global__ void k_build(const int* __restrict__ src, const int* __restrict__ dst,
                        int* __restrict__ cursor, int* __restrict__ colsrc, int E) {
  int stride = gridDim.x * blockDim.x;
  for (int e = blockIdx.x * blockDim.x + threadIdx.x; e < E; e += stride) {
    int d = dst[e];
    int p = atomicAdd(&cursor[d], 1);
    colsrc[p] = src[e];
  }
}

// ---------------- dense transform ----------------
// g[r,:] = bf16( dinv[r] * (x[r,:] @ W) )

template <int FIN, int FOUT, bool BF16IN>
__global__ void __launch_bounds__(256) k_transform(
    const void* __restrict__ xin, const float* __restrict__ Wg,
    const float* __restrict__ dinv, u16* __restrict__ g, int n) {
  constexpr int G = 64 / FOUT;   // node-groups per wave
  constexpr int RPB = 16 * G;    // rows per block
  constexpr int PAD = FIN + 4;   // 16B-aligned rows, staggers banks
  __shared__ float Ws[FIN * FOUT];
  __shared__ float xs[RPB * PAD];

  int t = threadIdx.x;
  for (int l = t; l < FIN * FOUT; l += THREADS) Ws[l] = Wg[l];

  int r0 = blockIdx.x * RPB;

  constexpr int TOT = RPB * FIN;
  for (int l = t * 4; l < TOT; l += THREADS * 4) {
    int row = l / FIN, k = l % FIN;
    int gr = r0 + row;
    float4 v = make_float4(0.f, 0.f, 0.f, 0.f);
    if (gr < n) {
      if constexpr (BF16IN) {
        const ushort4 u = *(const ushort4*)((const u16*)xin + (size_t)gr * FIN + k);
        v.x = bf2f(u.x); v.y = bf2f(u.y); v.z = bf2f(u.z); v.w = bf2f(u.w);
      } else {
        v = *(const float4*)((const float*)xin + (size_t)gr * FIN + k);
      }
    }
    *(float4*)&xs[row * PAD + k] = v;
  }
  __syncthreads();

  int ln = t & 63, wv = t >> 6;
  int col = ln % FOUT, grp = ln / FOUT;
  int lr = wv * 4 * G + grp * 4;  // 4 rows per lane
  const float* x0 = &xs[(lr + 0) * PAD];
  const float* x1 = &xs[(lr + 1) * PAD];
  const float* x2 = &xs[(lr + 2) * PAD];
  const float* x3 = &xs[(lr + 3) * PAD];

  float a0 = 0.f, a1 = 0.f, a2 = 0.f, a3 = 0.f;
#pragma unroll 16
  for (int k = 0; k < FIN; ++k) {
    float w = Ws[k * FOUT + col];
    a0 = fmaf(x0[k], w, a0);
    a1 = fmaf(x1[k], w, a1);
    a2 = fmaf(x2[k], w, a2);
    a3 = fmaf(x3[k], w, a3);
  }

  float vals[4] = {a0, a1, a2, a3};
  int gr = r0 + lr;
#pragma unroll
  for (int i = 0; i < 4; ++i) {
    int r = gr + i;
    if (r < n) g[(size_t)r * FOUT + col] = f2bf(vals[i] * dinv[r]);
  }
}

// ---------------- sparse gather + finalize ----------------
// f[d,:] = relu( (g[d,:] + sum_{s in N(d)} g[s,:]) * dinv[d] + b )

template <int F>
__global__ void __launch_bounds__(256) k_gather_fin(
    const u16* __restrict__ g, const int* __restrict__ rowptr,
    const int* __restrict__ colsrc, const float* __restrict__ dinv,
    const float* __restrict__ bias, u16* __restrict__ fout, int n) {
  constexpr int LPG = F / 4;   // lanes per node
  constexpr int G = 64 / LPG;  // nodes per wave
  int t = threadIdx.x;
  int ln = t & 63, wib = t >> 6;
  int lanein = ln % LPG, grp = ln / LPG;
  int f0 = lanein * 4;
  float b0 = bias[f0 + 0], b1 = bias[f0 + 1], b2 = bias[f0 + 2], b3 = bias[f0 + 3];
  int gw = blockIdx.x * (blockDim.x >> 6) + wib;
  int nwaves = (gridDim.x * blockDim.x) >> 6;
  for (int node = gw * G + grp; node < n; node += nwaves * G) {
    int b = rowptr[node], e = rowptr[node + 1];
    ushort4 u = *(const ushort4*)&g[(size_t)node * F + f0];  // self-loop
    float a0 = bf2f(u.x), a1 = bf2f(u.y), a2 = bf2f(u.z), a3 = bf2f(u.w);
    for (int i = b; i < e; ++i) {
      int s = colsrc[i];
      u = *(const ushort4*)&g[(size_t)s * F + f0];
      a0 += bf2f(u.x); a1 += bf2f(u.y); a2 += bf2f(u.z); a3 += bf2f(u.w);
    }
    float di = dinv[node];
    ushort4 o;
    o.x = f2bf(fmaxf(fmaf(a0, di, b0), 0.f));
    o.y = f2bf(fmaxf(fmaf(a1, di, b1), 0.f));
    o.z = f2bf(fmaxf(fmaf(a2, di, b2), 0.f));
    o.w = f2bf(fmaxf(fmaf(a3, di, b3), 0.f));
    *(ushort4*)&fout[(size_t)node * F + f0] = o;
  }
}

// ---------------- final FC over concat(f1,f2,f3) ----------------

__global__ void __launch_bounds__(256) k_fc(
    const u16* __restrict__ f1, const u16* __restrict__ f2,
    const u16* __restrict__ f3, const float* __restrict__ Wfc,
    const float* __restrict__ bfc, float* __restrict__ out, int n) {
  constexpr int FIN = 112, FOUT = 16, RPB = 64, PAD = 116;
  __shared__ float Ws[FIN * FOUT];
  __shared__ float xs[RPB * PAD];
  int t = threadIdx.x;
  for (int l = t; l < FIN * FOUT; l += THREADS) Ws[l] = Wfc[l];
  int r0 = blockIdx.x * RPB;

  for (int l = t * 4; l < RPB * 64; l += THREADS * 4) {
    int row = l >> 6, k = l & 63;
    int gr = r0 + row;
    float4 v = make_float4(0.f, 0.f, 0.f, 0.f);
    if (gr < n) {
      const ushort4 u = *(const ushort4*)&f1[(size_t)gr * 64 + k];
      v.x = bf2f(u.x); v.y = bf2f(u.y); v.z = bf2f(u.z); v.w = bf2f(u.w);
    }
    *(float4*)&xs[row * PAD + k] = v;
  }
  for (int l = t * 4; l < RPB * 32; l += THREADS * 4) {
    int row = l >> 5, k = l & 31;
    int gr = r0 + row;
    float4 v = make_float4(0.f, 0.f, 0.f, 0.f);
    if (gr < n) {
      const ushort4 u = *(const ushort4*)&f2[(size_t)gr * 32 + k];
      v.x = bf2f(u.x); v.y = bf2f(u.y); v.z = bf2f(u.z); v.w = bf2f(u.w);
    }
    *(float4*)&xs[row * PAD + 64 + k] = v;
  }
  for (int l = t * 4; l < RPB * 16; l += THREADS * 4) {
    int row = l >> 4, k = l & 15;
    int gr = r0 + row;
    float4 v = make_float4(0.f, 0.f, 0.f, 0.f);
    if (gr < n) {
      const ushort4 u = *(const ushort4*)&f3[(size_t)gr * 16 + k];
      v.x = bf2f(u.x); v.y = bf2f(u.y); v.z = bf2f(u.z); v.w = bf2f(u.w);
    }
    *(float4*)&xs[row * PAD + 96 + k] = v;
  }
  __syncthreads();

  int ln = t & 63, wv = t >> 6;
  int col = ln & 15, grp = ln >> 4;
  int lr = wv * 16 + grp * 4;
  const float* x0 = &xs[(lr + 0) * PAD];
  const float* x1 = &xs[(lr + 1) * PAD];
  const float* x2 = &xs[(lr + 2) * PAD];
  const float* x3 = &xs[(lr + 3) * PAD];
  float a0 = 0.f, a1 = 0.f, a2 = 0.f, a3 = 0.f;
#pragma unroll 16
  for (int k = 0; k < FIN; ++k) {
    float w = Ws[k * FOUT + col];
    a0 = fmaf(x0[k], w, a0);
    a1 = fmaf(x1[k], w, a1);
    a2 = fmaf(x2[k], w, a2);
    a3 = fmaf(x3[k], w, a3);
  }
  float vals[4] = {a0, a1, a2, a3};
  int gr = r0 + lr;
  float bb = bfc[col];
#pragma unroll
  for (int i = 0; i < 4; ++i) {
    int r = gr + i;
    if (r < n) out[(size_t)r * FOUT + col] = fmaxf(vals[i] + bb, 0.f);
  }
}

// ---------------- launch ----------------

extern "C" void kernel_launch(void* const* d_in, const int* in_sizes, int n_in,
                              void* d_out, int out_size, void* d_ws, size_t ws_size,
                              hipStream_t stream) {
  const int* edges = (const int*)d_in[0];
  const float* feat = (const float*)d_in[1];
  const float* W1 = (const float*)d_in[2];
  const float* b1 = (const float*)d_in[3];
  const float* W2 = (const float*)d_in[4];
  const float* b2 = (const float*)d_in[5];
  const float* W3 = (const float*)d_in[6];
  const float* b3 = (const float*)d_in[7];
  const float* Wfc = (const float*)d_in[8];
  const float* bfc = (const float*)d_in[9];
  float* out = (float*)d_out;

  const int E = in_sizes[0] / 2;
  const int n = in_sizes[1] / 128;
  const int* srcp = edges;
  const int* dstp = edges + E;

  char* w = (char*)d_ws;
  auto carve = [&](size_t bytes) {
    void* p = (void*)w;
    w += (bytes + 255) & ~(size_t)255;
    return p;
  };
  int* deg = (int*)carve((size_t)n * 4);
  int* rowptr = (int*)carve(((size_t)n + 1) * 4);
  int* cursor = (int*)carve((size_t)n * 4);
  int* colsrc = (int*)carve((size_t)E * 4);
  int* bsum = (int*)carve(512 * 4);
  float* dinv = (float*)carve((size_t)n * 4);
  u16* g = (u16*)carve((size_t)n * 64 * 2);   // shared by g1/g2/g3
  u16* f1 = (u16*)carve((size_t)n * 64 * 2);
  u16* f2 = (u16*)carve((size_t)n * 32 * 2);
  u16* f3 = (u16*)carve((size_t)n * 16 * 2);

  const int nb = (n + 255) / 256;  // 391 <= 512

  k_zero<<<nb, 256, 0, stream>>>(deg, n);
  k_count<<<1024, 256, 0, stream>>>(dstp, deg, E);
  k_scan1<<<nb, 256, 0, stream>>>(deg, rowptr, bsum, n);
  k_scan2<<<1, 512, 0, stream>>>(bsum, nb);
  k_scan3<<<nb, 256, 0, stream>>>(rowptr, cursor, bsum, deg, dinv, n, E);
  k_build<<<1024, 256, 0, stream>>>(srcp, dstp, cursor, colsrc, E);

  k_transform<128, 64, false><<<(n + 15) / 16, 256, 0, stream>>>(feat, W1, dinv, g, n);
  k_gather_fin<64><<<2048, 256, 0, stream>>>(g, rowptr, colsrc, dinv, b1, f1, n);

  k_transform<64, 32, true><<<(n + 31) / 32, 256, 0, stream>>>(f1, W2, dinv, g, n);
  k_gather_fin<32><<<2048, 256, 0, stream>>>(g, rowptr, colsrc, dinv, b2, f2, n);

  k_transform<32, 16, true><<<(n + 63) / 64, 256, 0, stream>>>(f2, W3, dinv, g, n);
  k_gather_fin<16><<<2048, 256, 0, stream>>>(g, rowptr, colsrc, dinv, b3, f3, n);

  k_fc<<<(n + 63) / 64, 256, 0, stream>>>(f1, f2, f3, Wfc, bfc, out, n);
}

// Round 3
// 426.318 us; speedup vs baseline: 1.0040x; 1.0040x over previous
//
#include <hip/hip_runtime.h>

#define THREADS 256

typedef unsigned short u16;

constexpr int BSH = 7;        // 128 nodes per bucket
constexpr int BN = 1 << BSH;  // 128
constexpr int PADI = 16;      // counter padding (64B) to spread L2 atomic slices

__device__ inline float bf2f(u16 u) {
  union { unsigned int i; float f; } c;
  c.i = ((unsigned int)u) << 16;
  return c.f;
}
__device__ inline u16 f2bf(float f) {
  union { float f; unsigned int i; } c;
  c.f = f;
  unsigned int r = c.i + 0x7fff + ((c.i >> 16) & 1);  // RNE
  return (u16)(r >> 16);
}

// ---------------- graph build (bucketed multisplit) ----------------

__global__ void k_zero(int* __restrict__ p, int n) {
  int i = blockIdx.x * blockDim.x + threadIdx.x;
  if (i < n) p[i] = 0;
}

__global__ void k_hist(const int* __restrict__ dst, int* __restrict__ bcnt, int E) {
  int stride = gridDim.x * blockDim.x;
  for (int e = blockIdx.x * blockDim.x + threadIdx.x; e < E; e += stride)
    atomicAdd(&bcnt[(dst[e] >> BSH) * PADI], 1);
}

__global__ void k_scanb(const int* __restrict__ bcnt, int* __restrict__ bbase,
                        int* __restrict__ bcur, int nbk, int E) {
  __shared__ int s[1024];
  int t = threadIdx.x;
  int v = (t < nbk) ? bcnt[t * PADI] : 0;
  s[t] = v;
  __syncthreads();
  for (int o = 1; o < 1024; o <<= 1) {
    int x = (t >= o) ? s[t - o] : 0;
    __syncthreads();
    s[t] += x;
    __syncthreads();
  }
  if (t < nbk) {
    int ex = s[t] - v;  // exclusive
    bbase[t] = ex;
    bcur[t * PADI] = ex;
  }
  if (t == nbk - 1) bbase[nbk] = s[t];  // == E
}

__global__ void k_part(const int* __restrict__ src, const int* __restrict__ dst,
                       int* __restrict__ bcur, int2* __restrict__ ebuf, int E) {
  int stride = gridDim.x * blockDim.x;
  for (int e = blockIdx.x * blockDim.x + threadIdx.x; e < E; e += stride) {
    int s = src[e], d = dst[e];
    int p = atomicAdd(&bcur[(d >> BSH) * PADI], 1);
    ebuf[p] = make_int2(s, d);
  }
}

// one block per bucket: LDS count -> rowptr/dinv (no global scan) -> LDS-cursor scatter
__global__ void __launch_bounds__(256) k_bucket(
    const int2* __restrict__ ebuf, const int* __restrict__ bbase,
    int* __restrict__ rowptr, int* __restrict__ colsrc,
    float* __restrict__ dinv, int n, int nbk, int E) {
  __shared__ int cnt[BN];
  __shared__ int sc[BN];
  __shared__ int cur[BN];
  int b = blockIdx.x, t = threadIdx.x;
  int beg = bbase[b], end = bbase[b + 1];
  if (t < BN) cnt[t] = 0;
  __syncthreads();
  for (int i = beg + t; i < end; i += 256)
    atomicAdd(&cnt[ebuf[i].y & (BN - 1)], 1);
  __syncthreads();
  int v = (t < BN) ? cnt[t] : 0;
  if (t < BN) sc[t] = v;
  __syncthreads();
  for (int o = 1; o < BN; o <<= 1) {
    int x = (t < BN && t >= o) ? sc[t - o] : 0;
    __syncthreads();
    if (t < BN) sc[t] += x;
    __syncthreads();
  }
  int node0 = b << BSH;
  if (t < BN) {
    int rp = beg + sc[t] - v;  // exclusive prefix + bucket base
    cur[t] = rp;
    int node = node0 + t;
    if (node < n) {
      rowptr[node] = rp;
      dinv[node] = rsqrtf((float)(v + 1));  // +1 self-loop
    }
  }
  if (b == nbk - 1 && t == 0) rowptr[n] = E;
  __syncthreads();
  for (int i = beg + t; i < end; i += 256) {
    int2 e = ebuf[i];
    int p = atomicAdd(&cur[e.y & (BN - 1)], 1);
    colsrc[p] = e.x;
  }
}

// ---------------- dense transform ----------------
// g[r,:] = bf16( dinv[r] * (x[r,:] @ W) )

template <int FIN, int FOUT, bool BF16IN>
__global__ void __launch_bounds__(256) k_transform(
    const void* __restrict__ xin, const float* __restrict__ Wg,
    const float* __restrict__ dinv, u16* __restrict__ g, int n) {
  constexpr int G = 64 / FOUT;
  constexpr int RPB = 16 * G;
  constexpr int PAD = FIN + 4;
  __shared__ float Ws[FIN * FOUT];
  __shared__ float xs[RPB * PAD];

  int t = threadIdx.x;
  for (int l = t; l < FIN * FOUT; l += THREADS) Ws[l] = Wg[l];

  int r0 = blockIdx.x * RPB;

  constexpr int TOT = RPB * FIN;
  for (int l = t * 4; l < TOT; l += THREADS * 4) {
    int row = l / FIN, k = l % FIN;
    int gr = r0 + row;
    float4 v = make_float4(0.f, 0.f, 0.f, 0.f);
    if (gr < n) {
      if constexpr (BF16IN) {
        const ushort4 u = *(const ushort4*)((const u16*)xin + (size_t)gr * FIN + k);
        v.x = bf2f(u.x); v.y = bf2f(u.y); v.z = bf2f(u.z); v.w = bf2f(u.w);
      } else {
        v = *(const float4*)((const float*)xin + (size_t)gr * FIN + k);
      }
    }
    *(float4*)&xs[row * PAD + k] = v;
  }
  __syncthreads();

  int ln = t & 63, wv = t >> 6;
  int col = ln % FOUT, grp = ln / FOUT;
  int lr = wv * 4 * G + grp * 4;
  const float* x0 = &xs[(lr + 0) * PAD];
  const float* x1 = &xs[(lr + 1) * PAD];
  const float* x2 = &xs[(lr + 2) * PAD];
  const float* x3 = &xs[(lr + 3) * PAD];

  float a0 = 0.f, a1 = 0.f, a2 = 0.f, a3 = 0.f;
#pragma unroll 16
  for (int k = 0; k < FIN; ++k) {
    float w = Ws[k * FOUT + col];
    a0 = fmaf(x0[k], w, a0);
    a1 = fmaf(x1[k], w, a1);
    a2 = fmaf(x2[k], w, a2);
    a3 = fmaf(x3[k], w, a3);
  }

  float vals[4] = {a0, a1, a2, a3};
  int gr = r0 + lr;
#pragma unroll
  for (int i = 0; i < 4; ++i) {
    int r = gr + i;
    if (r < n) g[(size_t)r * FOUT + col] = f2bf(vals[i] * dinv[r]);
  }
}

// ---------------- sparse gather + finalize ----------------

template <int F>
__global__ void __launch_bounds__(256) k_gather_fin(
    const u16* __restrict__ g, const int* __restrict__ rowptr,
    const int* __restrict__ colsrc, const float* __restrict__ dinv,
    const float* __restrict__ bias, u16* __restrict__ fout, int n) {
  constexpr int LPG = F / 4;
  constexpr int G = 64 / LPG;
  int t = threadIdx.x;
  int ln = t & 63, wib = t >> 6;
  int lanein = ln % LPG, grp = ln / LPG;
  int f0 = lanein * 4;
  float b0 = bias[f0 + 0], b1 = bias[f0 + 1], b2 = bias[f0 + 2], b3 = bias[f0 + 3];
  int gw = blockIdx.x * (blockDim.x >> 6) + wib;
  int nwaves = (gridDim.x * blockDim.x) >> 6;
  for (int node = gw * G + grp; node < n; node += nwaves * G) {
    int b = rowptr[node], e = rowptr[node + 1];
    ushort4 u = *(const ushort4*)&g[(size_t)node * F + f0];  // self-loop
    float a0 = bf2f(u.x), a1 = bf2f(u.y), a2 = bf2f(u.z), a3 = bf2f(u.w);
    for (int i = b; i < e; ++i) {
      int s = colsrc[i];
      u = *(const ushort4*)&g[(size_t)s * F + f0];
      a0 += bf2f(u.x); a1 += bf2f(u.y); a2 += bf2f(u.z); a3 += bf2f(u.w);
    }
    float di = dinv[node];
    ushort4 o;
    o.x = f2bf(fmaxf(fmaf(a0, di, b0), 0.f));
    o.y = f2bf(fmaxf(fmaf(a1, di, b1), 0.f));
    o.z = f2bf(fmaxf(fmaf(a2, di, b2), 0.f));
    o.w = f2bf(fmaxf(fmaf(a3, di, b3), 0.f));
    *(ushort4*)&fout[(size_t)node * F + f0] = o;
  }
}

// ---------------- final FC over concat(f1,f2,f3) ----------------

__global__ void __launch_bounds__(256) k_fc(
    const u16* __restrict__ f1, const u16* __restrict__ f2,
    const u16* __restrict__ f3, const float* __restrict__ Wfc,
    const float* __restrict__ bfc, float* __restrict__ out, int n) {
  constexpr int FIN = 112, FOUT = 16, RPB = 64, PAD = 116;
  __shared__ float Ws[FIN * FOUT];
  __shared__ float xs[RPB * PAD];
  int t = threadIdx.x;
  for (int l = t; l < FIN * FOUT; l += THREADS) Ws[l] = Wfc[l];
  int r0 = blockIdx.x * RPB;

  for (int l = t * 4; l < RPB * 64; l += THREADS * 4) {
    int row = l >> 6, k = l & 63;
    int gr = r0 + row;
    float4 v = make_float4(0.f, 0.f, 0.f, 0.f);
    if (gr < n) {
      const ushort4 u = *(const ushort4*)&f1[(size_t)gr * 64 + k];
      v.x = bf2f(u.x); v.y = bf2f(u.y); v.z = bf2f(u.z); v.w = bf2f(u.w);
    }
    *(float4*)&xs[row * PAD + k] = v;
  }
  for (int l = t * 4; l < RPB * 32; l += THREADS * 4) {
    int row = l >> 5, k = l & 31;
    int gr = r0 + row;
    float4 v = make_float4(0.f, 0.f, 0.f, 0.f);
    if (gr < n) {
      const ushort4 u = *(const ushort4*)&f2[(size_t)gr * 32 + k];
      v.x = bf2f(u.x); v.y = bf2f(u.y); v.z = bf2f(u.z); v.w = bf2f(u.w);
    }
    *(float4*)&xs[row * PAD + 64 + k] = v;
  }
  for (int l = t * 4; l < RPB * 16; l += THREADS * 4) {
    int row = l >> 4, k = l & 15;
    int gr = r0 + row;
    float4 v = make_float4(0.f, 0.f, 0.f, 0.f);
    if (gr < n) {
      const ushort4 u = *(const ushort4*)&f3[(size_t)gr * 16 + k];
      v.x = bf2f(u.x); v.y = bf2f(u.y); v.z = bf2f(u.z); v.w = bf2f(u.w);
    }
    *(float4*)&xs[row * PAD + 96 + k] = v;
  }
  __syncthreads();

  int ln = t & 63, wv = t >> 6;
  int col = ln & 15, grp = ln >> 4;
  int lr = wv * 16 + grp * 4;
  const float* x0 = &xs[(lr + 0) * PAD];
  const float* x1 = &xs[(lr + 1) * PAD];
  const float* x2 = &xs[(lr + 2) * PAD];
  const float* x3 = &xs[(lr + 3) * PAD];
  float a0 = 0.f, a1 = 0.f, a2 = 0.f, a3 = 0.f;
#pragma unroll 16
  for (int k = 0; k < FIN; ++k) {
    float w = Ws[k * FOUT + col];
    a0 = fmaf(x0[k], w, a0);
    a1 = fmaf(x1[k], w, a1);
    a2 = fmaf(x2[k], w, a2);
    a3 = fmaf(x3[k], w, a3);
  }
  float vals[4] = {a0, a1, a2, a3};
  int gr = r0 + lr;
  float bb = bfc[col];
#pragma unroll
  for (int i = 0; i < 4; ++i) {
    int r = gr + i;
    if (r < n) out[(size_t)r * FOUT + col] = fmaxf(vals[i] + bb, 0.f);
  }
}

// ---------------- launch ----------------

extern "C" void kernel_launch(void* const* d_in, const int* in_sizes, int n_in,
                              void* d_out, int out_size, void* d_ws, size_t ws_size,
                              hipStream_t stream) {
  const int* edges = (const int*)d_in[0];
  const float* feat = (const float*)d_in[1];
  const float* W1 = (const float*)d_in[2];
  const float* b1 = (const float*)d_in[3];
  const float* W2 = (const float*)d_in[4];
  const float* b2 = (const float*)d_in[5];
  const float* W3 = (const float*)d_in[6];
  const float* b3 = (const float*)d_in[7];
  const float* Wfc = (const float*)d_in[8];
  const float* bfc = (const float*)d_in[9];
  float* out = (float*)d_out;

  const int E = in_sizes[0] / 2;
  const int n = in_sizes[1] / 128;
  const int* srcp = edges;
  const int* dstp = edges + E;
  const int nbk = (n + BN - 1) >> BSH;

  char* w = (char*)d_ws;
  auto carve = [&](size_t bytes) {
    void* p = (void*)w;
    w += (bytes + 255) & ~(size_t)255;
    return p;
  };
  int* bcnt = (int*)carve((size_t)nbk * PADI * 4);
  int* bbase = (int*)carve(((size_t)nbk + 1) * 4);
  int* bcur = (int*)carve((size_t)nbk * PADI * 4);
  int* rowptr = (int*)carve(((size_t)n + 1) * 4);
  float* dinv = (float*)carve((size_t)n * 4);
  int* colsrc = (int*)carve((size_t)E * 4);
  // ebuf (E*8B) aliases g (n*64*2B): ebuf dead after k_bucket, g born at transform1
  size_t big = (size_t)E * 8 > (size_t)n * 128 ? (size_t)E * 8 : (size_t)n * 128;
  void* shared_big = carve(big);
  int2* ebuf = (int2*)shared_big;
  u16* g = (u16*)shared_big;
  u16* f1 = (u16*)carve((size_t)n * 64 * 2);
  u16* f2 = (u16*)carve((size_t)n * 32 * 2);
  u16* f3 = (u16*)carve((size_t)n * 16 * 2);

  k_zero<<<(nbk * PADI + 255) / 256, 256, 0, stream>>>(bcnt, nbk * PADI);
  k_hist<<<1024, 256, 0, stream>>>(dstp, bcnt, E);
  k_scanb<<<1, 1024, 0, stream>>>(bcnt, bbase, bcur, nbk, E);
  k_part<<<1024, 256, 0, stream>>>(srcp, dstp, bcur, ebuf, E);
  k_bucket<<<nbk, 256, 0, stream>>>(ebuf, bbase, rowptr, colsrc, dinv, n, nbk, E);

  k_transform<128, 64, false><<<(n + 15) / 16, 256, 0, stream>>>(feat, W1, dinv, g, n);
  k_gather_fin<64><<<2048, 256, 0, stream>>>(g, rowptr, colsrc, dinv, b1, f1, n);

  k_transform<64, 32, true><<<(n + 31) / 32, 256, 0, stream>>>(f1, W2, dinv, g, n);
  k_gather_fin<32><<<2048, 256, 0, stream>>>(g, rowptr, colsrc, dinv, b2, f2, n);

  k_transform<32, 16, true><<<(n + 63) / 64, 256, 0, stream>>>(f2, W3, dinv, g, n);
  k_gather_fin<16><<<2048, 256, 0, stream>>>(g, rowptr, colsrc, dinv, b3, f3, n);

  k_fc<<<(n + 63) / 64, 256, 0, stream>>>(f1, f2, f3, Wfc, bfc, out, n);
}

// Round 4
// 331.949 us; speedup vs baseline: 1.2895x; 1.2843x over previous
//
#include <hip/hip_runtime.h>

#define THREADS 256

typedef unsigned short u16;
typedef float f32x4 __attribute__((ext_vector_type(4)));
typedef short bf16x8 __attribute__((ext_vector_type(8)));

constexpr int SH = 9;          // 512 nodes per bucket
constexpr int NB = 1 << SH;    // 512
constexpr int TILE = 4096;     // edges per partition block

__device__ inline float bf2f(u16 u) {
  union { unsigned int i; float f; } c;
  c.i = ((unsigned int)u) << 16;
  return c.f;
}
__device__ inline u16 f2bf(float f) {
  union { float f; unsigned int i; } c;
  c.f = f;
  unsigned int r = c.i + 0x7fff + ((c.i >> 16) & 1);  // RNE
  return (u16)(r >> 16);
}

union V8 {
  bf16x8 v;
  short s[8];
  ushort4 u4[2];
};

// ---------------- graph build: tiled counting sort ----------------

__global__ void __launch_bounds__(256) k_hist(const int* __restrict__ dst,
                                              int* __restrict__ ghist, int E,
                                              int nblk, int nbk) {
  __shared__ int lcnt[NB];  // only nbk used (<=512)
  int t = threadIdx.x, blk = blockIdx.x;
  for (int i = t; i < nbk; i += 256) lcnt[i] = 0;
  __syncthreads();
  int beg = blk * TILE, end = min(beg + TILE, E);
  for (int e = beg + t; e < end; e += 256) atomicAdd(&lcnt[dst[e] >> SH], 1);
  __syncthreads();
  for (int i = t; i < nbk; i += 256) ghist[i * nblk + blk] = lcnt[i];
}

__global__ void __launch_bounds__(1024) k_scan(int* __restrict__ g, int total) {
  __shared__ int sc[1024];
  int t = threadIdx.x;
  int chunk = (total + 1023) / 1024;
  int beg = t * chunk, end = min(beg + chunk, total);
  int s = 0;
  for (int i = beg; i < end; ++i) s += g[i];
  sc[t] = s;
  __syncthreads();
  for (int o = 1; o < 1024; o <<= 1) {
    int x = (t >= o) ? sc[t - o] : 0;
    __syncthreads();
    sc[t] += x;
    __syncthreads();
  }
  int base = sc[t] - s;
  for (int i = beg; i < end; ++i) {
    int v = g[i];
    g[i] = base;
    base += v;
  }
}

__global__ void __launch_bounds__(256) k_part(const int* __restrict__ src,
                                              const int* __restrict__ dst,
                                              const int* __restrict__ goff,
                                              int* __restrict__ ebuf, int E,
                                              int nblk, int nbk) {
  __shared__ int lcur[NB];
  int t = threadIdx.x, blk = blockIdx.x;
  for (int i = t; i < nbk; i += 256) lcur[i] = goff[i * nblk + blk];
  __syncthreads();
  int beg = blk * TILE, end = min(beg + TILE, E);
  for (int e = beg + t; e < end; e += 256) {
    int s = src[e], d = dst[e];
    int p = atomicAdd(&lcur[d >> SH], 1);
    ebuf[p] = s | ((d & (NB - 1)) << 20);
  }
}

// one block per bucket: exact CSR + dinv, all bookkeeping in LDS
__global__ void __launch_bounds__(256) k_refine(
    const int* __restrict__ ebuf, const int* __restrict__ goff,
    int* __restrict__ rowptr, int* __restrict__ colsrc, float* __restrict__ dinv,
    int n, int nbk, int nblk, int E) {
  __shared__ int cnt[NB];
  __shared__ int cur[NB];
  __shared__ int sc[256];
  int b = blockIdx.x, t = threadIdx.x;
  int beg = goff[b * nblk];
  int end = (b + 1 < nbk) ? goff[(b + 1) * nblk] : E;
  cnt[t] = 0;
  cnt[t + 256] = 0;
  __syncthreads();
  for (int i = beg + t; i < end; i += 256) atomicAdd(&cnt[ebuf[i] >> 20], 1);
  __syncthreads();
  int c0 = cnt[2 * t], c1 = cnt[2 * t + 1];
  int a = c0 + c1;
  sc[t] = a;
  __syncthreads();
  for (int o = 1; o < 256; o <<= 1) {
    int x = (t >= o) ? sc[t - o] : 0;
    __syncthreads();
    sc[t] += x;
    __syncthreads();
  }
  int base0 = beg + sc[t] - a;  // exclusive
  int base1 = base0 + c0;
  int node0 = b << SH;
  int n0 = node0 + 2 * t, n1 = n0 + 1;
  cur[2 * t] = base0;
  cur[2 * t + 1] = base1;
  if (n0 <= n) rowptr[n0] = base0;
  if (n1 <= n) rowptr[n1] = base1;
  if (n0 < n) dinv[n0] = rsqrtf((float)(c0 + 1));
  if (n1 < n) dinv[n1] = rsqrtf((float)(c1 + 1));
  __syncthreads();
  for (int i = beg + t; i < end; i += 256) {
    int w = ebuf[i];
    int p = atomicAdd(&cur[w >> 20], 1);
    colsrc[p] = w & 0xFFFFF;
  }
}

// ---------------- MFMA dense transform ----------------
// g[r,:] = bf16( dinv[r] * (x[r,:] @ W) ); block = 128 rows, wave = 32 rows

template <int KC, int FOUT, bool BF16IN>
__global__ void __launch_bounds__(256) k_xform(
    const void* __restrict__ xin, const float* __restrict__ Wg,
    const float* __restrict__ dinv, u16* __restrict__ g, int n) {
  constexpr int FIN = KC * 32;
  constexpr int NC = FOUT / 16;
  constexpr int ASLOTS = 8 * KC * 64;   // 128 rows
  constexpr int WSLOTS = KC * NC * 64;
  __shared__ short xa[ASLOTS * 8];
  __shared__ short wb[WSLOTS * 8];

  int t = threadIdx.x;
  int r0 = blockIdx.x * 128;

  // stage W in fragment order (bf16)
  for (int s = t; s < WSLOTS; s += 256) {
    int lane = s & 63, q = s >> 6;
    int nc = q % NC, kc = q / NC;
    int col = nc * 16 + (lane & 15);
    int kr = kc * 32 + (lane >> 4) * 8;
    V8 v;
#pragma unroll
    for (int j = 0; j < 8; ++j) v.s[j] = (short)f2bf(Wg[(kr + j) * FOUT + col]);
    *(bf16x8*)&wb[s * 8] = v.v;
  }

  // stage A in fragment order
  for (int s = t; s < ASLOTS; s += 256) {
    int lane = s & 63, q = s >> 6;
    int kc = q % KC, mtile = q / KC;
    int row = mtile * 16 + (lane & 15);
    int k = kc * 32 + (lane >> 4) * 8;
    int gr = r0 + row;
    V8 v;
    if (gr < n) {
      if constexpr (BF16IN) {
        v.v = *(const bf16x8*)((const u16*)xin + (size_t)gr * FIN + k);
      } else {
        const float* xf = (const float*)xin + (size_t)gr * FIN + k;
        float4 p = *(const float4*)xf;
        float4 q4 = *(const float4*)(xf + 4);
        v.s[0] = (short)f2bf(p.x); v.s[1] = (short)f2bf(p.y);
        v.s[2] = (short)f2bf(p.z); v.s[3] = (short)f2bf(p.w);
        v.s[4] = (short)f2bf(q4.x); v.s[5] = (short)f2bf(q4.y);
        v.s[6] = (short)f2bf(q4.z); v.s[7] = (short)f2bf(q4.w);
      }
    } else {
      for (int j = 0; j < 8; ++j) v.s[j] = 0;
    }
    *(bf16x8*)&xa[s * 8] = v.v;
  }
  __syncthreads();

  int ln = t & 63, wv = t >> 6;
  int m0 = wv * 2;

  bf16x8 bf[KC * NC];
#pragma unroll
  for (int i = 0; i < KC * NC; ++i) bf[i] = *(const bf16x8*)&wb[(i * 64 + ln) * 8];

  f32x4 acc[2][NC];
#pragma unroll
  for (int i = 0; i < 2; ++i)
#pragma unroll
    for (int j = 0; j < NC; ++j) acc[i][j] = {0.f, 0.f, 0.f, 0.f};

#pragma unroll
  for (int kc = 0; kc < KC; ++kc) {
    bf16x8 a0 = *(const bf16x8*)&xa[(((m0 + 0) * KC + kc) * 64 + ln) * 8];
    bf16x8 a1 = *(const bf16x8*)&xa[(((m0 + 1) * KC + kc) * 64 + ln) * 8];
#pragma unroll
    for (int nc = 0; nc < NC; ++nc) {
      acc[0][nc] = __builtin_amdgcn_mfma_f32_16x16x32_bf16(a0, bf[kc * NC + nc], acc[0][nc], 0, 0, 0);
      acc[1][nc] = __builtin_amdgcn_mfma_f32_16x16x32_bf16(a1, bf[kc * NC + nc], acc[1][nc], 0, 0, 0);
    }
  }

  int colb = ln & 15, rq = ln >> 4;
#pragma unroll
  for (int mt2 = 0; mt2 < 2; ++mt2) {
#pragma unroll
    for (int reg = 0; reg < 4; ++reg) {
      int gr = r0 + (m0 + mt2) * 16 + rq * 4 + reg;
      if (gr < n) {
        float di = dinv[gr];
#pragma unroll
        for (int nc = 0; nc < NC; ++nc)
          g[(size_t)gr * FOUT + nc * 16 + colb] = f2bf(acc[mt2][nc][reg] * di);
      }
    }
  }
}

// ---------------- sparse gather + finalize ----------------

template <int F>
__global__ void __launch_bounds__(256) k_gather_fin(
    const u16* __restrict__ g, const int* __restrict__ rowptr,
    const int* __restrict__ colsrc, const float* __restrict__ dinv,
    const float* __restrict__ bias, u16* __restrict__ fout, int n) {
  constexpr int LPG = F / 4;
  constexpr int G = 64 / LPG;
  int t = threadIdx.x;
  int ln = t & 63, wib = t >> 6;
  int lanein = ln % LPG, grp = ln / LPG;
  int f0 = lanein * 4;
  float b0 = bias[f0 + 0], b1 = bias[f0 + 1], b2 = bias[f0 + 2], b3 = bias[f0 + 3];
  int gw = blockIdx.x * (blockDim.x >> 6) + wib;
  int nwaves = (gridDim.x * blockDim.x) >> 6;
  for (int node = gw * G + grp; node < n; node += nwaves * G) {
    int b = rowptr[node], e = rowptr[node + 1];
    ushort4 u = *(const ushort4*)&g[(size_t)node * F + f0];  // self-loop
    float a0 = bf2f(u.x), a1 = bf2f(u.y), a2 = bf2f(u.z), a3 = bf2f(u.w);
    for (int i = b; i < e; ++i) {
      int s = colsrc[i];
      u = *(const ushort4*)&g[(size_t)s * F + f0];
      a0 += bf2f(u.x); a1 += bf2f(u.y); a2 += bf2f(u.z); a3 += bf2f(u.w);
    }
    float di = dinv[node];
    ushort4 o;
    o.x = f2bf(fmaxf(fmaf(a0, di, b0), 0.f));
    o.y = f2bf(fmaxf(fmaf(a1, di, b1), 0.f));
    o.z = f2bf(fmaxf(fmaf(a2, di, b2), 0.f));
    o.w = f2bf(fmaxf(fmaf(a3, di, b3), 0.f));
    *(ushort4*)&fout[(size_t)node * F + f0] = o;
  }
}

// ---------------- FC over concat(f1,f2,f3), MFMA, K padded 112->128 ----------------

__global__ void __launch_bounds__(256) k_fc(
    const u16* __restrict__ f1, const u16* __restrict__ f2,
    const u16* __restrict__ f3, const float* __restrict__ Wfc,
    const float* __restrict__ bfc, float* __restrict__ out, int n) {
  constexpr int KC = 4, FOUT = 16;
  constexpr int ASLOTS = 8 * KC * 64;
  constexpr int WSLOTS = KC * 64;
  __shared__ short xa[ASLOTS * 8];
  __shared__ short wb[WSLOTS * 8];

  int t = threadIdx.x;
  int r0 = blockIdx.x * 128;

  for (int s = t; s < WSLOTS; s += 256) {
    int lane = s & 63, kc = s >> 6;
    int col = lane & 15;
    int kr = kc * 32 + (lane >> 4) * 8;
    V8 v;
#pragma unroll
    for (int j = 0; j < 8; ++j)
      v.s[j] = (kr + j < 112) ? (short)f2bf(Wfc[(kr + j) * FOUT + col]) : (short)0;
    *(bf16x8*)&wb[s * 8] = v.v;
  }

  for (int s = t; s < ASLOTS; s += 256) {
    int lane = s & 63, q = s >> 6;
    int kc = q & 3, mtile = q >> 2;
    int row = mtile * 16 + (lane & 15);
    int k = kc * 32 + (lane >> 4) * 8;
    int gr = r0 + row;
    V8 v;
    if (gr < n && k < 112) {
      if (k < 64) v.v = *(const bf16x8*)&f1[(size_t)gr * 64 + k];
      else if (k < 96) v.v = *(const bf16x8*)&f2[(size_t)gr * 32 + (k - 64)];
      else v.v = *(const bf16x8*)&f3[(size_t)gr * 16 + (k - 96)];
    } else {
      for (int j = 0; j < 8; ++j) v.s[j] = 0;
    }
    *(bf16x8*)&xa[s * 8] = v.v;
  }
  __syncthreads();

  int ln = t & 63, wv = t >> 6;
  int m0 = wv * 2;

  bf16x8 bf[KC];
#pragma unroll
  for (int i = 0; i < KC; ++i) bf[i] = *(const bf16x8*)&wb[(i * 64 + ln) * 8];

  f32x4 acc[2] = {{0.f, 0.f, 0.f, 0.f}, {0.f, 0.f, 0.f, 0.f}};
#pragma unroll
  for (int kc = 0; kc < KC; ++kc) {
    bf16x8 a0 = *(const bf16x8*)&xa[(((m0 + 0) * KC + kc) * 64 + ln) * 8];
    bf16x8 a1 = *(const bf16x8*)&xa[(((m0 + 1) * KC + kc) * 64 + ln) * 8];
    acc[0] = __builtin_amdgcn_mfma_f32_16x16x32_bf16(a0, bf[kc], acc[0], 0, 0, 0);
    acc[1] = __builtin_amdgcn_mfma_f32_16x16x32_bf16(a1, bf[kc], acc[1], 0, 0, 0);
  }

  int colb = ln & 15, rq = ln >> 4;
  float bb = bfc[colb];
#pragma unroll
  for (int mt2 = 0; mt2 < 2; ++mt2) {
#pragma unroll
    for (int reg = 0; reg < 4; ++reg) {
      int gr = r0 + (m0 + mt2) * 16 + rq * 4 + reg;
      if (gr < n) out[(size_t)gr * 16 + colb] = fmaxf(acc[mt2][reg] + bb, 0.f);
    }
  }
}

// ---------------- launch ----------------

extern "C" void kernel_launch(void* const* d_in, const int* in_sizes, int n_in,
                              void* d_out, int out_size, void* d_ws, size_t ws_size,
                              hipStream_t stream) {
  const int* edges = (const int*)d_in[0];
  const float* feat = (const float*)d_in[1];
  const float* W1 = (const float*)d_in[2];
  const float* b1 = (const float*)d_in[3];
  const float* W2 = (const float*)d_in[4];
  const float* b2 = (const float*)d_in[5];
  const float* W3 = (const float*)d_in[6];
  const float* b3 = (const float*)d_in[7];
  const float* Wfc = (const float*)d_in[8];
  const float* bfc = (const float*)d_in[9];
  float* out = (float*)d_out;

  const int E = in_sizes[0] / 2;
  const int n = in_sizes[1] / 128;
  const int* srcp = edges;
  const int* dstp = edges + E;
  const int nbk = (n + NB - 1) >> SH;          // 196
  const int nblk = (E + TILE - 1) / TILE;      // 391

  char* w = (char*)d_ws;
  auto carve = [&](size_t bytes) {
    void* p = (void*)w;
    w += (bytes + 255) & ~(size_t)255;
    return p;
  };
  int* ghist = (int*)carve((size_t)nbk * nblk * 4);
  int* rowptr = (int*)carve(((size_t)n + 1) * 4);
  float* dinv = (float*)carve((size_t)n * 4);
  int* colsrc = (int*)carve((size_t)E * 4);
  // ebuf (E*4B) aliases g (n*64*2B): ebuf dead after k_refine, g born at transform1
  size_t big = (size_t)E * 4 > (size_t)n * 128 ? (size_t)E * 4 : (size_t)n * 128;
  void* shared_big = carve(big);
  int* ebuf = (int*)shared_big;
  u16* g = (u16*)shared_big;
  u16* f1 = (u16*)carve((size_t)n * 64 * 2);
  u16* f2 = (u16*)carve((size_t)n * 32 * 2);
  u16* f3 = (u16*)carve((size_t)n * 16 * 2);

  k_hist<<<nblk, 256, 0, stream>>>(dstp, ghist, E, nblk, nbk);
  k_scan<<<1, 1024, 0, stream>>>(ghist, nbk * nblk);
  k_part<<<nblk, 256, 0, stream>>>(srcp, dstp, ghist, ebuf, E, nblk, nbk);
  k_refine<<<nbk, 256, 0, stream>>>(ebuf, ghist, rowptr, colsrc, dinv, n, nbk, nblk, E);

  const int xb = (n + 127) / 128;  // 782

  k_xform<4, 64, false><<<xb, 256, 0, stream>>>(feat, W1, dinv, g, n);
  k_gather_fin<64><<<2048, 256, 0, stream>>>(g, rowptr, colsrc, dinv, b1, f1, n);

  k_xform<2, 32, true><<<xb, 256, 0, stream>>>(f1, W2, dinv, g, n);
  k_gather_fin<32><<<2048, 256, 0, stream>>>(g, rowptr, colsrc, dinv, b2, f2, n);

  k_xform<1, 16, true><<<xb, 256, 0, stream>>>(f2, W3, dinv, g, n);
  k_gather_fin<16><<<2048, 256, 0, stream>>>(g, rowptr, colsrc, dinv, b3, f3, n);

  k_fc<<<xb, 256, 0, stream>>>(f1, f2, f3, Wfc, bfc, out, n);
}

// Round 5
// 215.178 us; speedup vs baseline: 1.9892x; 1.5427x over previous
//
#include <hip/hip_runtime.h>

#define THREADS 256

typedef unsigned short u16;
typedef float f32x4 __attribute__((ext_vector_type(4)));
typedef short bf16x8 __attribute__((ext_vector_type(8)));

constexpr int SH = 9;          // 512 nodes per bucket
constexpr int NB = 1 << SH;    // 512
constexpr int TILE = 4096;     // edges per partition block

__device__ inline float bf2f(u16 u) {
  union { unsigned int i; float f; } c;
  c.i = ((unsigned int)u) << 16;
  return c.f;
}
__device__ inline u16 f2bf(float f) {
  union { float f; unsigned int i; } c;
  c.f = f;
  unsigned int r = c.i + 0x7fff + ((c.i >> 16) & 1);  // RNE
  return (u16)(r >> 16);
}

union V8 {
  bf16x8 v;
  short s[8];
  ushort4 u4[2];
};

// ---------------- graph build: tiled counting sort ----------------

__global__ void __launch_bounds__(256) k_hist(const int* __restrict__ dst,
                                              int* __restrict__ ghist, int E,
                                              int nblk, int nbk) {
  __shared__ int lcnt[NB];  // only nbk used (<=512)
  int t = threadIdx.x, blk = blockIdx.x;
  for (int i = t; i < nbk; i += 256) lcnt[i] = 0;
  __syncthreads();
  int beg = blk * TILE, end = min(beg + TILE, E);
  for (int e = beg + t; e < end; e += 256) atomicAdd(&lcnt[dst[e] >> SH], 1);
  __syncthreads();
  for (int i = t; i < nbk; i += 256) ghist[i * nblk + blk] = lcnt[i];
}

// per-bucket row scan: exclusive within row, total -> bsum[bucket]
__global__ void __launch_bounds__(256) k_scanA(int* __restrict__ ghist,
                                               int* __restrict__ bsum, int nblk) {
  __shared__ int sc[256];
  int i = blockIdx.x, t = threadIdx.x;
  int* row = ghist + (size_t)i * nblk;
  int e0 = 2 * t, e1 = 2 * t + 1;
  int a0 = (e0 < nblk) ? row[e0] : 0;
  int a1 = (e1 < nblk) ? row[e1] : 0;
  int s = a0 + a1;
  sc[t] = s;
  __syncthreads();
  for (int o = 1; o < 256; o <<= 1) {
    int x = (t >= o) ? sc[t - o] : 0;
    __syncthreads();
    sc[t] += x;
    __syncthreads();
  }
  int base = sc[t] - s;  // exclusive
  if (e0 < nblk) row[e0] = base;
  if (e1 < nblk) row[e1] = base + a0;
  if (t == 255) bsum[i] = sc[255];
}

// scan of bucket totals (nbk <= 256)
__global__ void __launch_bounds__(256) k_scanB(const int* __restrict__ bsum,
                                               int* __restrict__ bbase, int nbk) {
  __shared__ int sc[256];
  int t = threadIdx.x;
  int v = (t < nbk) ? bsum[t] : 0;
  sc[t] = v;
  __syncthreads();
  for (int o = 1; o < 256; o <<= 1) {
    int x = (t >= o) ? sc[t - o] : 0;
    __syncthreads();
    sc[t] += x;
    __syncthreads();
  }
  if (t < nbk) bbase[t] = sc[t] - v;
}

__global__ void __launch_bounds__(256) k_part(const int* __restrict__ src,
                                              const int* __restrict__ dst,
                                              const int* __restrict__ goff,
                                              const int* __restrict__ bbase,
                                              int* __restrict__ ebuf, int E,
                                              int nblk, int nbk) {
  __shared__ int lcur[NB];
  int t = threadIdx.x, blk = blockIdx.x;
  for (int i = t; i < nbk; i += 256) lcur[i] = goff[(size_t)i * nblk + blk] + bbase[i];
  __syncthreads();
  int beg = blk * TILE, end = min(beg + TILE, E);
  for (int e = beg + t; e < end; e += 256) {
    int s = src[e], d = dst[e];
    int p = atomicAdd(&lcur[d >> SH], 1);
    ebuf[p] = s | ((d & (NB - 1)) << 20);
  }
}

// one block per bucket: exact CSR + dinv, all bookkeeping in LDS
__global__ void __launch_bounds__(256) k_refine(
    const int* __restrict__ ebuf, const int* __restrict__ goff,
    const int* __restrict__ bbase, int* __restrict__ rowptr,
    int* __restrict__ colsrc, float* __restrict__ dinv,
    int n, int nbk, int nblk, int E) {
  __shared__ int cnt[NB];
  __shared__ int cur[NB];
  __shared__ int sc[256];
  int b = blockIdx.x, t = threadIdx.x;
  int beg = goff[(size_t)b * nblk] + bbase[b];
  int end = (b + 1 < nbk) ? goff[(size_t)(b + 1) * nblk] + bbase[b + 1] : E;
  cnt[t] = 0;
  cnt[t + 256] = 0;
  __syncthreads();
  for (int i = beg + t; i < end; i += 256) atomicAdd(&cnt[ebuf[i] >> 20], 1);
  __syncthreads();
  int c0 = cnt[2 * t], c1 = cnt[2 * t + 1];
  int a = c0 + c1;
  sc[t] = a;
  __syncthreads();
  for (int o = 1; o < 256; o <<= 1) {
    int x = (t >= o) ? sc[t - o] : 0;
    __syncthreads();
    sc[t] += x;
    __syncthreads();
  }
  int base0 = beg + sc[t] - a;  // exclusive
  int base1 = base0 + c0;
  int node0 = b << SH;
  int n0 = node0 + 2 * t, n1 = n0 + 1;
  cur[2 * t] = base0;
  cur[2 * t + 1] = base1;
  if (n0 <= n) rowptr[n0] = base0;
  if (n1 <= n) rowptr[n1] = base1;
  if (n0 < n) dinv[n0] = rsqrtf((float)(c0 + 1));
  if (n1 < n) dinv[n1] = rsqrtf((float)(c1 + 1));
  __syncthreads();
  for (int i = beg + t; i < end; i += 256) {
    int w = ebuf[i];
    int p = atomicAdd(&cur[w >> 20], 1);
    colsrc[p] = w & 0xFFFFF;
  }
}

// ---------------- MFMA dense transform ----------------
// g[r,:] = bf16( dinv[r] * (x[r,:] @ W) ); block = 128 rows, wave = 32 rows

template <int KC, int FOUT, bool BF16IN>
__global__ void __launch_bounds__(256) k_xform(
    const void* __restrict__ xin, const float* __restrict__ Wg,
    const float* __restrict__ dinv, u16* __restrict__ g, int n) {
  constexpr int FIN = KC * 32;
  constexpr int NC = FOUT / 16;
  constexpr int ASLOTS = 8 * KC * 64;   // 128 rows
  constexpr int WSLOTS = KC * NC * 64;
  __shared__ short xa[ASLOTS * 8];
  __shared__ short wb[WSLOTS * 8];

  int t = threadIdx.x;
  int r0 = blockIdx.x * 128;

  // stage W in fragment order (bf16)
  for (int s = t; s < WSLOTS; s += 256) {
    int lane = s & 63, q = s >> 6;
    int nc = q % NC, kc = q / NC;
    int col = nc * 16 + (lane & 15);
    int kr = kc * 32 + (lane >> 4) * 8;
    V8 v;
#pragma unroll
    for (int j = 0; j < 8; ++j) v.s[j] = (short)f2bf(Wg[(kr + j) * FOUT + col]);
    *(bf16x8*)&wb[s * 8] = v.v;
  }

  // stage A in fragment order
  for (int s = t; s < ASLOTS; s += 256) {
    int lane = s & 63, q = s >> 6;
    int kc = q % KC, mtile = q / KC;
    int row = mtile * 16 + (lane & 15);
    int k = kc * 32 + (lane >> 4) * 8;
    int gr = r0 + row;
    V8 v;
    if (gr < n) {
      if constexpr (BF16IN) {
        v.v = *(const bf16x8*)((const u16*)xin + (size_t)gr * FIN + k);
      } else {
        const float* xf = (const float*)xin + (size_t)gr * FIN + k;
        float4 p = *(const float4*)xf;
        float4 q4 = *(const float4*)(xf + 4);
        v.s[0] = (short)f2bf(p.x); v.s[1] = (short)f2bf(p.y);
        v.s[2] = (short)f2bf(p.z); v.s[3] = (short)f2bf(p.w);
        v.s[4] = (short)f2bf(q4.x); v.s[5] = (short)f2bf(q4.y);
        v.s[6] = (short)f2bf(q4.z); v.s[7] = (short)f2bf(q4.w);
      }
    } else {
      for (int j = 0; j < 8; ++j) v.s[j] = 0;
    }
    *(bf16x8*)&xa[s * 8] = v.v;
  }
  __syncthreads();

  int ln = t & 63, wv = t >> 6;
  int m0 = wv * 2;

  bf16x8 bf[KC * NC];
#pragma unroll
  for (int i = 0; i < KC * NC; ++i) bf[i] = *(const bf16x8*)&wb[(i * 64 + ln) * 8];

  f32x4 acc[2][NC];
#pragma unroll
  for (int i = 0; i < 2; ++i)
#pragma unroll
    for (int j = 0; j < NC; ++j) acc[i][j] = {0.f, 0.f, 0.f, 0.f};

#pragma unroll
  for (int kc = 0; kc < KC; ++kc) {
    bf16x8 a0 = *(const bf16x8*)&xa[(((m0 + 0) * KC + kc) * 64 + ln) * 8];
    bf16x8 a1 = *(const bf16x8*)&xa[(((m0 + 1) * KC + kc) * 64 + ln) * 8];
#pragma unroll
    for (int nc = 0; nc < NC; ++nc) {
      acc[0][nc] = __builtin_amdgcn_mfma_f32_16x16x32_bf16(a0, bf[kc * NC + nc], acc[0][nc], 0, 0, 0);
      acc[1][nc] = __builtin_amdgcn_mfma_f32_16x16x32_bf16(a1, bf[kc * NC + nc], acc[1][nc], 0, 0, 0);
    }
  }

  int colb = ln & 15, rq = ln >> 4;
#pragma unroll
  for (int mt2 = 0; mt2 < 2; ++mt2) {
#pragma unroll
    for (int reg = 0; reg < 4; ++reg) {
      int gr = r0 + (m0 + mt2) * 16 + rq * 4 + reg;
      if (gr < n) {
        float di = dinv[gr];
#pragma unroll
        for (int nc = 0; nc < NC; ++nc)
          g[(size_t)gr * FOUT + nc * 16 + colb] = f2bf(acc[mt2][nc][reg] * di);
      }
    }
  }
}

// ---------------- sparse gather + finalize ----------------

template <int F>
__global__ void __launch_bounds__(256) k_gather_fin(
    const u16* __restrict__ g, const int* __restrict__ rowptr,
    const int* __restrict__ colsrc, const float* __restrict__ dinv,
    const float* __restrict__ bias, u16* __restrict__ fout, int n) {
  constexpr int LPG = F / 4;
  constexpr int G = 64 / LPG;
  int t = threadIdx.x;
  int ln = t & 63, wib = t >> 6;
  int lanein = ln % LPG, grp = ln / LPG;
  int f0 = lanein * 4;
  float b0 = bias[f0 + 0], b1 = bias[f0 + 1], b2 = bias[f0 + 2], b3 = bias[f0 + 3];
  int gw = blockIdx.x * (blockDim.x >> 6) + wib;
  int nwaves = (gridDim.x * blockDim.x) >> 6;
  for (int node = gw * G + grp; node < n; node += nwaves * G) {
    int b = rowptr[node], e = rowptr[node + 1];
    ushort4 u = *(const ushort4*)&g[(size_t)node * F + f0];  // self-loop
    float a0 = bf2f(u.x), a1 = bf2f(u.y), a2 = bf2f(u.z), a3 = bf2f(u.w);
    for (int i = b; i < e; ++i) {
      int s = colsrc[i];
      u = *(const ushort4*)&g[(size_t)s * F + f0];
      a0 += bf2f(u.x); a1 += bf2f(u.y); a2 += bf2f(u.z); a3 += bf2f(u.w);
    }
    float di = dinv[node];
    ushort4 o;
    o.x = f2bf(fmaxf(fmaf(a0, di, b0), 0.f));
    o.y = f2bf(fmaxf(fmaf(a1, di, b1), 0.f));
    o.z = f2bf(fmaxf(fmaf(a2, di, b2), 0.f));
    o.w = f2bf(fmaxf(fmaf(a3, di, b3), 0.f));
    *(ushort4*)&fout[(size_t)node * F + f0] = o;
  }
}

// ---------------- FC over concat(f1,f2,f3), MFMA, K padded 112->128 ----------------

__global__ void __launch_bounds__(256) k_fc(
    const u16* __restrict__ f1, const u16* __restrict__ f2,
    const u16* __restrict__ f3, const float* __restrict__ Wfc,
    const float* __restrict__ bfc, float* __restrict__ out, int n) {
  constexpr int KC = 4, FOUT = 16;
  constexpr int ASLOTS = 8 * KC * 64;
  constexpr int WSLOTS = KC * 64;
  __shared__ short xa[ASLOTS * 8];
  __shared__ short wb[WSLOTS * 8];

  int t = threadIdx.x;
  int r0 = blockIdx.x * 128;

  for (int s = t; s < WSLOTS; s += 256) {
    int lane = s & 63, kc = s >> 6;
    int col = lane & 15;
    int kr = kc * 32 + (lane >> 4) * 8;
    V8 v;
#pragma unroll
    for (int j = 0; j < 8; ++j)
      v.s[j] = (kr + j < 112) ? (short)f2bf(Wfc[(kr + j) * FOUT + col]) : (short)0;
    *(bf16x8*)&wb[s * 8] = v.v;
  }

  for (int s = t; s < ASLOTS; s += 256) {
    int lane = s & 63, q = s >> 6;
    int kc = q & 3, mtile = q >> 2;
    int row = mtile * 16 + (lane & 15);
    int k = kc * 32 + (lane >> 4) * 8;
    int gr = r0 + row;
    V8 v;
    if (gr < n && k < 112) {
      if (k < 64) v.v = *(const bf16x8*)&f1[(size_t)gr * 64 + k];
      else if (k < 96) v.v = *(const bf16x8*)&f2[(size_t)gr * 32 + (k - 64)];
      else v.v = *(const bf16x8*)&f3[(size_t)gr * 16 + (k - 96)];
    } else {
      for (int j = 0; j < 8; ++j) v.s[j] = 0;
    }
    *(bf16x8*)&xa[s * 8] = v.v;
  }
  __syncthreads();

  int ln = t & 63, wv = t >> 6;
  int m0 = wv * 2;

  bf16x8 bf[KC];
#pragma unroll
  for (int i = 0; i < KC; ++i) bf[i] = *(const bf16x8*)&wb[(i * 64 + ln) * 8];

  f32x4 acc[2] = {{0.f, 0.f, 0.f, 0.f}, {0.f, 0.f, 0.f, 0.f}};
#pragma unroll
  for (int kc = 0; kc < KC; ++kc) {
    bf16x8 a0 = *(const bf16x8*)&xa[(((m0 + 0) * KC + kc) * 64 + ln) * 8];
    bf16x8 a1 = *(const bf16x8*)&xa[(((m0 + 1) * KC + kc) * 64 + ln) * 8];
    acc[0] = __builtin_amdgcn_mfma_f32_16x16x32_bf16(a0, bf[kc], acc[0], 0, 0, 0);
    acc[1] = __builtin_amdgcn_mfma_f32_16x16x32_bf16(a1, bf[kc], acc[1], 0, 0, 0);
  }

  int colb = ln & 15, rq = ln >> 4;
  float bb = bfc[colb];
#pragma unroll
  for (int mt2 = 0; mt2 < 2; ++mt2) {
#pragma unroll
    for (int reg = 0; reg < 4; ++reg) {
      int gr = r0 + (m0 + mt2) * 16 + rq * 4 + reg;
      if (gr < n) out[(size_t)gr * 16 + colb] = fmaxf(acc[mt2][reg] + bb, 0.f);
    }
  }
}

// ---------------- launch ----------------

extern "C" void kernel_launch(void* const* d_in, const int* in_sizes, int n_in,
                              void* d_out, int out_size, void* d_ws, size_t ws_size,
                              hipStream_t stream) {
  const int* edges = (const int*)d_in[0];
  const float* feat = (const float*)d_in[1];
  const float* W1 = (const float*)d_in[2];
  const float* b1 = (const float*)d_in[3];
  const float* W2 = (const float*)d_in[4];
  const float* b2 = (const float*)d_in[5];
  const float* W3 = (const float*)d_in[6];
  const float* b3 = (const float*)d_in[7];
  const float* Wfc = (const float*)d_in[8];
  const float* bfc = (const float*)d_in[9];
  float* out = (float*)d_out;

  const int E = in_sizes[0] / 2;
  const int n = in_sizes[1] / 128;
  const int* srcp = edges;
  const int* dstp = edges + E;
  const int nbk = (n + NB - 1) >> SH;          // 196 (<=256 required by k_scanB)
  const int nblk = (E + TILE - 1) / TILE;      // 391 (<=512 required by k_scanA)

  char* w = (char*)d_ws;
  auto carve = [&](size_t bytes) {
    void* p = (void*)w;
    w += (bytes + 255) & ~(size_t)255;
    return p;
  };
  int* ghist = (int*)carve((size_t)nbk * nblk * 4);
  int* bsum = (int*)carve(256 * 4);
  int* bbase = (int*)carve(256 * 4);
  int* rowptr = (int*)carve(((size_t)n + 1) * 4);
  float* dinv = (float*)carve((size_t)n * 4);
  int* colsrc = (int*)carve((size_t)E * 4);
  // ebuf (E*4B) aliases g (n*64*2B): ebuf dead after k_refine, g born at transform1
  size_t big = (size_t)E * 4 > (size_t)n * 128 ? (size_t)E * 4 : (size_t)n * 128;
  void* shared_big = carve(big);
  int* ebuf = (int*)shared_big;
  u16* g = (u16*)shared_big;
  u16* f1 = (u16*)carve((size_t)n * 64 * 2);
  u16* f2 = (u16*)carve((size_t)n * 32 * 2);
  u16* f3 = (u16*)carve((size_t)n * 16 * 2);

  k_hist<<<nblk, 256, 0, stream>>>(dstp, ghist, E, nblk, nbk);
  k_scanA<<<nbk, 256, 0, stream>>>(ghist, bsum, nblk);
  k_scanB<<<1, 256, 0, stream>>>(bsum, bbase, nbk);
  k_part<<<nblk, 256, 0, stream>>>(srcp, dstp, ghist, bbase, ebuf, E, nblk, nbk);
  k_refine<<<nbk, 256, 0, stream>>>(ebuf, ghist, bbase, rowptr, colsrc, dinv, n, nbk, nblk, E);

  const int xb = (n + 127) / 128;  // 782

  k_xform<4, 64, false><<<xb, 256, 0, stream>>>(feat, W1, dinv, g, n);
  k_gather_fin<64><<<2048, 256, 0, stream>>>(g, rowptr, colsrc, dinv, b1, f1, n);

  k_xform<2, 32, true><<<xb, 256, 0, stream>>>(f1, W2, dinv, g, n);
  k_gather_fin<32><<<2048, 256, 0, stream>>>(g, rowptr, colsrc, dinv, b2, f2, n);

  k_xform<1, 16, true><<<xb, 256, 0, stream>>>(f2, W3, dinv, g, n);
  k_gather_fin<16><<<2048, 256, 0, stream>>>(g, rowptr, colsrc, dinv, b3, f3, n);

  k_fc<<<xb, 256, 0, stream>>>(f1, f2, f3, Wfc, bfc, out, n);
}

// Round 6
// 169.238 us; speedup vs baseline: 2.5292x; 1.2715x over previous
//
#include <hip/hip_runtime.h>

#define THREADS 256

typedef unsigned short u16;
typedef float f32x4 __attribute__((ext_vector_type(4)));
typedef short bf16x8 __attribute__((ext_vector_type(8)));

constexpr int SH = 9;          // 512 nodes per bucket
constexpr int NB = 1 << SH;    // 512
constexpr int TILE = 4096;     // edges per partition block

__device__ inline float bf2f(u16 u) {
  union { unsigned int i; float f; } c;
  c.i = ((unsigned int)u) << 16;
  return c.f;
}
__device__ inline u16 f2bf(float f) {
  union { float f; unsigned int i; } c;
  c.f = f;
  unsigned int r = c.i + 0x7fff + ((c.i >> 16) & 1);  // RNE
  return (u16)(r >> 16);
}

union V8 {
  bf16x8 v;
  short s[8];
  ushort4 u4[2];
};

// ---------------- graph build: tiled counting sort ----------------

__global__ void __launch_bounds__(256) k_hist(const int* __restrict__ dst,
                                              int* __restrict__ ghist, int E,
                                              int nblk, int nbk) {
  __shared__ int lcnt[NB];  // only nbk used (<=512)
  int t = threadIdx.x, blk = blockIdx.x;
  for (int i = t; i < nbk; i += 256) lcnt[i] = 0;
  __syncthreads();
  int beg = blk * TILE, end = min(beg + TILE, E);
  for (int e = beg + t; e < end; e += 256) atomicAdd(&lcnt[dst[e] >> SH], 1);
  __syncthreads();
  for (int i = t; i < nbk; i += 256) ghist[i * nblk + blk] = lcnt[i];
}

// per-bucket row scan: exclusive within row, total -> bsum[bucket]
__global__ void __launch_bounds__(256) k_scanA(int* __restrict__ ghist,
                                               int* __restrict__ bsum, int nblk) {
  __shared__ int sc[256];
  int i = blockIdx.x, t = threadIdx.x;
  int* row = ghist + (size_t)i * nblk;
  int e0 = 2 * t, e1 = 2 * t + 1;
  int a0 = (e0 < nblk) ? row[e0] : 0;
  int a1 = (e1 < nblk) ? row[e1] : 0;
  int s = a0 + a1;
  sc[t] = s;
  __syncthreads();
  for (int o = 1; o < 256; o <<= 1) {
    int x = (t >= o) ? sc[t - o] : 0;
    __syncthreads();
    sc[t] += x;
    __syncthreads();
  }
  int base = sc[t] - s;  // exclusive
  if (e0 < nblk) row[e0] = base;
  if (e1 < nblk) row[e1] = base + a0;
  if (t == 255) bsum[i] = sc[255];
}

// scan of bucket totals (nbk <= 256)
__global__ void __launch_bounds__(256) k_scanB(const int* __restrict__ bsum,
                                               int* __restrict__ bbase, int nbk) {
  __shared__ int sc[256];
  int t = threadIdx.x;
  int v = (t < nbk) ? bsum[t] : 0;
  sc[t] = v;
  __syncthreads();
  for (int o = 1; o < 256; o <<= 1) {
    int x = (t >= o) ? sc[t - o] : 0;
    __syncthreads();
    sc[t] += x;
    __syncthreads();
  }
  if (t < nbk) bbase[t] = sc[t] - v;
}

__global__ void __launch_bounds__(256) k_part(const int* __restrict__ src,
                                              const int* __restrict__ dst,
                                              const int* __restrict__ goff,
                                              const int* __restrict__ bbase,
                                              int* __restrict__ ebuf, int E,
                                              int nblk, int nbk) {
  __shared__ int lcur[NB];
  int t = threadIdx.x, blk = blockIdx.x;
  for (int i = t; i < nbk; i += 256) lcur[i] = goff[(size_t)i * nblk + blk] + bbase[i];
  __syncthreads();
  int beg = blk * TILE, end = min(beg + TILE, E);
  for (int e = beg + t; e < end; e += 256) {
    int s = src[e], d = dst[e];
    int p = atomicAdd(&lcur[d >> SH], 1);
    ebuf[p] = s | ((d & (NB - 1)) << 20);
  }
}

// one block per bucket: exact CSR + dinv, all bookkeeping in LDS
__global__ void __launch_bounds__(256) k_refine(
    const int* __restrict__ ebuf, const int* __restrict__ goff,
    const int* __restrict__ bbase, int* __restrict__ rowptr,
    int* __restrict__ colsrc, float* __restrict__ dinv,
    int n, int nbk, int nblk, int E) {
  __shared__ int cnt[NB];
  __shared__ int cur[NB];
  __shared__ int sc[256];
  int b = blockIdx.x, t = threadIdx.x;
  int beg = goff[(size_t)b * nblk] + bbase[b];
  int end = (b + 1 < nbk) ? goff[(size_t)(b + 1) * nblk] + bbase[b + 1] : E;
  cnt[t] = 0;
  cnt[t + 256] = 0;
  __syncthreads();
  for (int i = beg + t; i < end; i += 256) atomicAdd(&cnt[ebuf[i] >> 20], 1);
  __syncthreads();
  int c0 = cnt[2 * t], c1 = cnt[2 * t + 1];
  int a = c0 + c1;
  sc[t] = a;
  __syncthreads();
  for (int o = 1; o < 256; o <<= 1) {
    int x = (t >= o) ? sc[t - o] : 0;
    __syncthreads();
    sc[t] += x;
    __syncthreads();
  }
  int base0 = beg + sc[t] - a;  // exclusive
  int base1 = base0 + c0;
  int node0 = b << SH;
  int n0 = node0 + 2 * t, n1 = n0 + 1;
  cur[2 * t] = base0;
  cur[2 * t + 1] = base1;
  if (n0 <= n) rowptr[n0] = base0;
  if (n1 <= n) rowptr[n1] = base1;
  if (n0 < n) dinv[n0] = rsqrtf((float)(c0 + 1));
  if (n1 < n) dinv[n1] = rsqrtf((float)(c1 + 1));
  __syncthreads();
  for (int i = beg + t; i < end; i += 256) {
    int w = ebuf[i];
    int p = atomicAdd(&cur[w >> 20], 1);
    colsrc[p] = w & 0xFFFFF;
  }
}

// ---------------- MFMA dense transform ----------------
// g[r,:] = bf16( dinv[r] * (x[r,:] @ W) ); block = 128 rows, wave = 32 rows

template <int KC, int FOUT, bool BF16IN>
__global__ void __launch_bounds__(256) k_xform(
    const void* __restrict__ xin, const float* __restrict__ Wg,
    const float* __restrict__ dinv, u16* __restrict__ g, int n) {
  constexpr int FIN = KC * 32;
  constexpr int NC = FOUT / 16;
  constexpr int ASLOTS = 8 * KC * 64;   // 128 rows
  constexpr int WSLOTS = KC * NC * 64;
  __shared__ short xa[ASLOTS * 8];
  __shared__ short wb[WSLOTS * 8];

  int t = threadIdx.x;
  int r0 = blockIdx.x * 128;

  // stage W in fragment order (bf16)
  for (int s = t; s < WSLOTS; s += 256) {
    int lane = s & 63, q = s >> 6;
    int nc = q % NC, kc = q / NC;
    int col = nc * 16 + (lane & 15);
    int kr = kc * 32 + (lane >> 4) * 8;
    V8 v;
#pragma unroll
    for (int j = 0; j < 8; ++j) v.s[j] = (short)f2bf(Wg[(kr + j) * FOUT + col]);
    *(bf16x8*)&wb[s * 8] = v.v;
  }

  // stage A in fragment order
  for (int s = t; s < ASLOTS; s += 256) {
    int lane = s & 63, q = s >> 6;
    int kc = q % KC, mtile = q / KC;
    int row = mtile * 16 + (lane & 15);
    int k = kc * 32 + (lane >> 4) * 8;
    int gr = r0 + row;
    V8 v;
    if (gr < n) {
      if constexpr (BF16IN) {
        v.v = *(const bf16x8*)((const u16*)xin + (size_t)gr * FIN + k);
      } else {
        const float* xf = (const float*)xin + (size_t)gr * FIN + k;
        float4 p = *(const float4*)xf;
        float4 q4 = *(const float4*)(xf + 4);
        v.s[0] = (short)f2bf(p.x); v.s[1] = (short)f2bf(p.y);
        v.s[2] = (short)f2bf(p.z); v.s[3] = (short)f2bf(p.w);
        v.s[4] = (short)f2bf(q4.x); v.s[5] = (short)f2bf(q4.y);
        v.s[6] = (short)f2bf(q4.z); v.s[7] = (short)f2bf(q4.w);
      }
    } else {
      for (int j = 0; j < 8; ++j) v.s[j] = 0;
    }
    *(bf16x8*)&xa[s * 8] = v.v;
  }
  __syncthreads();

  int ln = t & 63, wv = t >> 6;
  int m0 = wv * 2;

  bf16x8 bf[KC * NC];
#pragma unroll
  for (int i = 0; i < KC * NC; ++i) bf[i] = *(const bf16x8*)&wb[(i * 64 + ln) * 8];

  f32x4 acc[2][NC];
#pragma unroll
  for (int i = 0; i < 2; ++i)
#pragma unroll
    for (int j = 0; j < NC; ++j) acc[i][j] = {0.f, 0.f, 0.f, 0.f};

#pragma unroll
  for (int kc = 0; kc < KC; ++kc) {
    bf16x8 a0 = *(const bf16x8*)&xa[(((m0 + 0) * KC + kc) * 64 + ln) * 8];
    bf16x8 a1 = *(const bf16x8*)&xa[(((m0 + 1) * KC + kc) * 64 + ln) * 8];
#pragma unroll
    for (int nc = 0; nc < NC; ++nc) {
      acc[0][nc] = __builtin_amdgcn_mfma_f32_16x16x32_bf16(a0, bf[kc * NC + nc], acc[0][nc], 0, 0, 0);
      acc[1][nc] = __builtin_amdgcn_mfma_f32_16x16x32_bf16(a1, bf[kc * NC + nc], acc[1][nc], 0, 0, 0);
    }
  }

  int colb = ln & 15, rq = ln >> 4;
#pragma unroll
  for (int mt2 = 0; mt2 < 2; ++mt2) {
#pragma unroll
    for (int reg = 0; reg < 4; ++reg) {
      int gr = r0 + (m0 + mt2) * 16 + rq * 4 + reg;
      if (gr < n) {
        float di = dinv[gr];
#pragma unroll
        for (int nc = 0; nc < NC; ++nc)
          g[(size_t)gr * FOUT + nc * 16 + colb] = f2bf(acc[mt2][nc][reg] * di);
      }
    }
  }
}

// ---------------- sparse gather + finalize (4-way ILP unroll) ----------------

template <int F>
__global__ void __launch_bounds__(256) k_gather_fin(
    const u16* __restrict__ g, const int* __restrict__ rowptr,
    const int* __restrict__ colsrc, const float* __restrict__ dinv,
    const float* __restrict__ bias, u16* __restrict__ fout, int n) {
  constexpr int LPG = F / 4;
  constexpr int G = 64 / LPG;
  int t = threadIdx.x;
  int ln = t & 63, wib = t >> 6;
  int lanein = ln % LPG, grp = ln / LPG;
  int f0 = lanein * 4;
  float b0 = bias[f0 + 0], b1 = bias[f0 + 1], b2 = bias[f0 + 2], b3 = bias[f0 + 3];
  int gw = blockIdx.x * (blockDim.x >> 6) + wib;
  int nwaves = (gridDim.x * blockDim.x) >> 6;
  for (int node = gw * G + grp; node < n; node += nwaves * G) {
    int b = rowptr[node], e = rowptr[node + 1];
    // 4 independent accumulator chains
    float p0[4] = {0.f, 0.f, 0.f, 0.f};
    float p1[4] = {0.f, 0.f, 0.f, 0.f};
    float p2[4] = {0.f, 0.f, 0.f, 0.f};
    float p3[4] = {0.f, 0.f, 0.f, 0.f};
    {  // self-loop into chain 0
      ushort4 u = *(const ushort4*)&g[(size_t)node * F + f0];
      p0[0] = bf2f(u.x); p0[1] = bf2f(u.y); p0[2] = bf2f(u.z); p0[3] = bf2f(u.w);
    }
    int i = b;
    for (; i + 4 <= e; i += 4) {
      int s0 = colsrc[i + 0], s1 = colsrc[i + 1];
      int s2 = colsrc[i + 2], s3 = colsrc[i + 3];
      ushort4 u0 = *(const ushort4*)&g[(size_t)s0 * F + f0];
      ushort4 u1 = *(const ushort4*)&g[(size_t)s1 * F + f0];
      ushort4 u2 = *(const ushort4*)&g[(size_t)s2 * F + f0];
      ushort4 u3 = *(const ushort4*)&g[(size_t)s3 * F + f0];
      p0[0] += bf2f(u0.x); p0[1] += bf2f(u0.y); p0[2] += bf2f(u0.z); p0[3] += bf2f(u0.w);
      p1[0] += bf2f(u1.x); p1[1] += bf2f(u1.y); p1[2] += bf2f(u1.z); p1[3] += bf2f(u1.w);
      p2[0] += bf2f(u2.x); p2[1] += bf2f(u2.y); p2[2] += bf2f(u2.z); p2[3] += bf2f(u2.w);
      p3[0] += bf2f(u3.x); p3[1] += bf2f(u3.y); p3[2] += bf2f(u3.z); p3[3] += bf2f(u3.w);
    }
    for (; i < e; ++i) {
      int s = colsrc[i];
      ushort4 u = *(const ushort4*)&g[(size_t)s * F + f0];
      p1[0] += bf2f(u.x); p1[1] += bf2f(u.y); p1[2] += bf2f(u.z); p1[3] += bf2f(u.w);
    }
    float a0 = (p0[0] + p1[0]) + (p2[0] + p3[0]);
    float a1 = (p0[1] + p1[1]) + (p2[1] + p3[1]);
    float a2 = (p0[2] + p1[2]) + (p2[2] + p3[2]);
    float a3 = (p0[3] + p1[3]) + (p2[3] + p3[3]);
    float di = dinv[node];
    ushort4 o;
    o.x = f2bf(fmaxf(fmaf(a0, di, b0), 0.f));
    o.y = f2bf(fmaxf(fmaf(a1, di, b1), 0.f));
    o.z = f2bf(fmaxf(fmaf(a2, di, b2), 0.f));
    o.w = f2bf(fmaxf(fmaf(a3, di, b3), 0.f));
    *(ushort4*)&fout[(size_t)node * F + f0] = o;
  }
}

// ---------------- FC over concat(f1,f2,f3), MFMA, K padded 112->128 ----------------

__global__ void __launch_bounds__(256) k_fc(
    const u16* __restrict__ f1, const u16* __restrict__ f2,
    const u16* __restrict__ f3, const float* __restrict__ Wfc,
    const float* __restrict__ bfc, float* __restrict__ out, int n) {
  constexpr int KC = 4, FOUT = 16;
  constexpr int ASLOTS = 8 * KC * 64;
  constexpr int WSLOTS = KC * 64;
  __shared__ short xa[ASLOTS * 8];
  __shared__ short wb[WSLOTS * 8];

  int t = threadIdx.x;
  int r0 = blockIdx.x * 128;

  for (int s = t; s < WSLOTS; s += 256) {
    int lane = s & 63, kc = s >> 6;
    int col = lane & 15;
    int kr = kc * 32 + (lane >> 4) * 8;
    V8 v;
#pragma unroll
    for (int j = 0; j < 8; ++j)
      v.s[j] = (kr + j < 112) ? (short)f2bf(Wfc[(kr + j) * FOUT + col]) : (short)0;
    *(bf16x8*)&wb[s * 8] = v.v;
  }

  for (int s = t; s < ASLOTS; s += 256) {
    int lane = s & 63, q = s >> 6;
    int kc = q & 3, mtile = q >> 2;
    int row = mtile * 16 + (lane & 15);
    int k = kc * 32 + (lane >> 4) * 8;
    int gr = r0 + row;
    V8 v;
    if (gr < n && k < 112) {
      if (k < 64) v.v = *(const bf16x8*)&f1[(size_t)gr * 64 + k];
      else if (k < 96) v.v = *(const bf16x8*)&f2[(size_t)gr * 32 + (k - 64)];
      else v.v = *(const bf16x8*)&f3[(size_t)gr * 16 + (k - 96)];
    } else {
      for (int j = 0; j < 8; ++j) v.s[j] = 0;
    }
    *(bf16x8*)&xa[s * 8] = v.v;
  }
  __syncthreads();

  int ln = t & 63, wv = t >> 6;
  int m0 = wv * 2;

  bf16x8 bf[KC];
#pragma unroll
  for (int i = 0; i < KC; ++i) bf[i] = *(const bf16x8*)&wb[(i * 64 + ln) * 8];

  f32x4 acc[2] = {{0.f, 0.f, 0.f, 0.f}, {0.f, 0.f, 0.f, 0.f}};
#pragma unroll
  for (int kc = 0; kc < KC; ++kc) {
    bf16x8 a0 = *(const bf16x8*)&xa[(((m0 + 0) * KC + kc) * 64 + ln) * 8];
    bf16x8 a1 = *(const bf16x8*)&xa[(((m0 + 1) * KC + kc) * 64 + ln) * 8];
    acc[0] = __builtin_amdgcn_mfma_f32_16x16x32_bf16(a0, bf[kc], acc[0], 0, 0, 0);
    acc[1] = __builtin_amdgcn_mfma_f32_16x16x32_bf16(a1, bf[kc], acc[1], 0, 0, 0);
  }

  int colb = ln & 15, rq = ln >> 4;
  float bb = bfc[colb];
#pragma unroll
  for (int mt2 = 0; mt2 < 2; ++mt2) {
#pragma unroll
    for (int reg = 0; reg < 4; ++reg) {
      int gr = r0 + (m0 + mt2) * 16 + rq * 4 + reg;
      if (gr < n) out[(size_t)gr * 16 + colb] = fmaxf(acc[mt2][reg] + bb, 0.f);
    }
  }
}

// ---------------- launch ----------------

extern "C" void kernel_launch(void* const* d_in, const int* in_sizes, int n_in,
                              void* d_out, int out_size, void* d_ws, size_t ws_size,
                              hipStream_t stream) {
  const int* edges = (const int*)d_in[0];
  const float* feat = (const float*)d_in[1];
  const float* W1 = (const float*)d_in[2];
  const float* b1 = (const float*)d_in[3];
  const float* W2 = (const float*)d_in[4];
  const float* b2 = (const float*)d_in[5];
  const float* W3 = (const float*)d_in[6];
  const float* b3 = (const float*)d_in[7];
  const float* Wfc = (const float*)d_in[8];
  const float* bfc = (const float*)d_in[9];
  float* out = (float*)d_out;

  const int E = in_sizes[0] / 2;
  const int n = in_sizes[1] / 128;
  const int* srcp = edges;
  const int* dstp = edges + E;
  const int nbk = (n + NB - 1) >> SH;          // 196 (<=256 required by k_scanB)
  const int nblk = (E + TILE - 1) / TILE;      // 391 (<=512 required by k_scanA)

  char* w = (char*)d_ws;
  auto carve = [&](size_t bytes) {
    void* p = (void*)w;
    w += (bytes + 255) & ~(size_t)255;
    return p;
  };
  int* ghist = (int*)carve((size_t)nbk * nblk * 4);
  int* bsum = (int*)carve(256 * 4);
  int* bbase = (int*)carve(256 * 4);
  int* rowptr = (int*)carve(((size_t)n + 1) * 4);
  float* dinv = (float*)carve((size_t)n * 4);
  int* colsrc = (int*)carve((size_t)E * 4);
  // ebuf (E*4B) aliases g (n*64*2B): ebuf dead after k_refine, g born at transform1
  size_t big = (size_t)E * 4 > (size_t)n * 128 ? (size_t)E * 4 : (size_t)n * 128;
  void* shared_big = carve(big);
  int* ebuf = (int*)shared_big;
  u16* g = (u16*)shared_big;
  u16* f1 = (u16*)carve((size_t)n * 64 * 2);
  u16* f2 = (u16*)carve((size_t)n * 32 * 2);
  u16* f3 = (u16*)carve((size_t)n * 16 * 2);

  k_hist<<<nblk, 256, 0, stream>>>(dstp, ghist, E, nblk, nbk);
  k_scanA<<<nbk, 256, 0, stream>>>(ghist, bsum, nblk);
  k_scanB<<<1, 256, 0, stream>>>(bsum, bbase, nbk);
  k_part<<<nblk, 256, 0, stream>>>(srcp, dstp, ghist, bbase, ebuf, E, nblk, nbk);
  k_refine<<<nbk, 256, 0, stream>>>(ebuf, ghist, bbase, rowptr, colsrc, dinv, n, nbk, nblk, E);

  const int xb = (n + 127) / 128;  // 782

  k_xform<4, 64, false><<<xb, 256, 0, stream>>>(feat, W1, dinv, g, n);
  k_gather_fin<64><<<2048, 256, 0, stream>>>(g, rowptr, colsrc, dinv, b1, f1, n);

  k_xform<2, 32, true><<<xb, 256, 0, stream>>>(f1, W2, dinv, g, n);
  k_gather_fin<32><<<2048, 256, 0, stream>>>(g, rowptr, colsrc, dinv, b2, f2, n);

  k_xform<1, 16, true><<<xb, 256, 0, stream>>>(f2, W3, dinv, g, n);
  k_gather_fin<16><<<2048, 256, 0, stream>>>(g, rowptr, colsrc, dinv, b3, f3, n);

  k_fc<<<xb, 256, 0, stream>>>(f1, f2, f3, Wfc, bfc, out, n);
}